// Round 2
// baseline (1327.518 us; speedup 1.0000x reference)
//
#include <hip/hip_runtime.h>

// Ragged segment mean pooling: features [N, D=512] f32 -> out [B, D] f32.
// Memory-bound: 1.07 GB read -> ~170 us floor at 6.3 TB/s achievable HBM BW.
//
// R1 analysis: harness reset (4.3 GB ws poison + input restore) is ~1020 us of
// the measured 1313 us; kernel share ~290 us. This version streams each block
// over a CONTIGUOUS row chunk (sequential DRAM access like the 6.3 TB/s fill
// kernels) with a 4x-unrolled loop of independent float4 accumulators to
// maximize loads in flight.

#define SPLIT 256   // blocks per segment
#define TPB   128   // TPB * 4 floats = D = 512 (one full row per iteration)

__global__ __launch_bounds__(TPB) void seg_mean_kernel(
        const int* __restrict__ lens,
        const float* __restrict__ feat,
        float* __restrict__ out) {
    const int D = 512;
    const int seg   = blockIdx.x / SPLIT;
    const int split = blockIdx.x % SPLIT;

    // Segment start via tiny prefix loop (B=16; lens hits scalar cache).
    long long start = 0;
    for (int b = 0; b < seg; ++b) start += lens[b];
    const int len = lens[seg];

    // Contiguous chunk of rows for this block: sequential streaming.
    const int chunk = (len + SPLIT - 1) / SPLIT;
    const int r0 = split * chunk;
    const int r1 = (r0 + chunk < len) ? (r0 + chunk) : len;
    const int nrows = r1 - r0;

    const int col = threadIdx.x * 4;
    const float* base = feat + (start + (long long)r0) * D + col;

    float4 a0 = make_float4(0.f, 0.f, 0.f, 0.f);
    float4 a1 = a0, a2 = a0, a3 = a0;

    int r = 0;
    // 4x unroll, independent accumulators -> 4 outstanding 16B loads/thread.
    for (; r + 4 <= nrows; r += 4) {
        float4 v0 = *(const float4*)(base + (long long)(r + 0) * D);
        float4 v1 = *(const float4*)(base + (long long)(r + 1) * D);
        float4 v2 = *(const float4*)(base + (long long)(r + 2) * D);
        float4 v3 = *(const float4*)(base + (long long)(r + 3) * D);
        a0.x += v0.x; a0.y += v0.y; a0.z += v0.z; a0.w += v0.w;
        a1.x += v1.x; a1.y += v1.y; a1.z += v1.z; a1.w += v1.w;
        a2.x += v2.x; a2.y += v2.y; a2.z += v2.z; a2.w += v2.w;
        a3.x += v3.x; a3.y += v3.y; a3.z += v3.z; a3.w += v3.w;
    }
    for (; r < nrows; ++r) {
        float4 v = *(const float4*)(base + (long long)r * D);
        a0.x += v.x; a0.y += v.y; a0.z += v.z; a0.w += v.w;
    }

    a0.x += a1.x + a2.x + a3.x;
    a0.y += a1.y + a2.y + a3.y;
    a0.z += a1.z + a2.z + a3.z;
    a0.w += a1.w + a2.w + a3.w;

    // Fold mean's divide into the partial before the atomic.
    const float inv = (len > 0) ? (1.0f / (float)len) : 0.0f;
    float* o = out + (long long)seg * D + col;
    if (nrows > 0) {
        atomicAdd(o + 0, a0.x * inv);
        atomicAdd(o + 1, a0.y * inv);
        atomicAdd(o + 2, a0.z * inv);
        atomicAdd(o + 3, a0.w * inv);
    }
}

extern "C" void kernel_launch(void* const* d_in, const int* in_sizes, int n_in,
                              void* d_out, int out_size, void* d_ws, size_t ws_size,
                              hipStream_t stream) {
    const int*   lens = (const int*)d_in[0];     // stack_lengths [B] int32
    const float* feat = (const float*)d_in[1];   // features [N, D] float32
    float*       out  = (float*)d_out;           // [B, D] float32
    const int B = in_sizes[0];

    // d_out is poisoned to 0xAA before every call: zero it (async, in-stream,
    // graph-capture safe) before the atomic accumulation.
    hipMemsetAsync(out, 0, (size_t)out_size * sizeof(float), stream);

    seg_mean_kernel<<<B * SPLIT, TPB, 0, stream>>>(lens, feat, out);
}